// Round 4
// baseline (4221.967 us; speedup 1.0000x reference)
//
#include <hip/hip_runtime.h>
#include <cstdint>

// Sparse BasicBlock via bf16 MFMA implicit GEMM (32x32x16).
// Round 4: SINGLE-buffered LDS (58 KB) so TWO blocks co-reside per CU
// (16 waves/CU). Simple stage->drain->compute loop; cross-block implicit
// overlap hides the drain (m97/m114 pattern). All 448 blocks resident in
// one dispatch round (was 2 sequential rounds at 116 KB LDS).
//   xm,u layout: [img][chunk16][half2][row58][col58][c8]  (halo zero) — staging
//   order == storage order, so every global_load_lds is fully coalesced.
//   u   = mask * vector * relu(bn1(conv1(x * mask_dilate)))
//   out = relu(x + mask * bn2(conv2(u)))                      [NCHW f32]

#define EPS 1e-5f

constexpr int Bn = 32, Cc = 256, Hh = 56, Ww = 56;
constexpr int HW = Hh * Ww;                 // 3136
constexpr int PD = 58;                      // padded H/W
constexpr int SLAB = PD * PD * 8;           // elems per [row][col][c8] slab = 26912
constexpr int IMG_ELEMS = 16 * 2 * SLAB;    // 861184 elems per image
constexpr int WP_ELEMS = 2 * 16 * 9 * 2 * 128 * 8;   // 589824 per conv

typedef __bf16 bf16x8 __attribute__((ext_vector_type(8)));
typedef float  f32x16 __attribute__((ext_vector_type(16)));

// ---- pack x*mask_dilate -> chunk-major staged bf16, halo zeros ----
__global__ void pack_xm(const float* __restrict__ x, const float* __restrict__ md,
                        __bf16* __restrict__ xm) {
    int prow = blockIdx.x, img = blockIdx.y;
    int gy = prow - 1;
    bool rv = (unsigned)gy < 56u;
    for (int u = threadIdx.x; u < 32 * 64; u += 256) {
        int cg = u >> 6, pcol = u & 63;          // cg = chunk*2+half (32 groups of 8ch)
        if (pcol >= PD) continue;
        int gx = pcol - 1;
        bf16x8 v = {};
        if (rv && (unsigned)gx < 56u) {
            float mdv = md[img * HW + gy * 56 + gx];
            const float* xp = x + ((size_t)img * Cc + cg * 8) * HW + gy * 56 + gx;
            #pragma unroll
            for (int j = 0; j < 8; ++j)
                v[j] = (__bf16)(xp[(size_t)j * HW] * mdv);
        }
        *(bf16x8*)&xm[(size_t)(img * 32 + cg) * SLAB + (prow * PD + pcol) * 8] = v;
    }
}

// ---- zero the halo of u (rows 0,57; cols 0,57 of every slab) ----
__global__ void zero_u_halo(__bf16* __restrict__ u) {
    int img = blockIdx.x;
    __bf16* base = u + (size_t)img * IMG_ELEMS;
    bf16x8 z = {};
    for (int t = threadIdx.x; t < 32 * 228; t += 256) {
        int slab = t / 228, site = t - slab * 228;
        int prow, pcol;
        if (site < 58)       { prow = 0;          pcol = site; }
        else if (site < 116) { prow = 57;         pcol = site - 58; }
        else if (site < 172) { prow = site - 115; pcol = 0; }
        else                 { prow = site - 171; pcol = 57; }
        *(bf16x8*)&base[(size_t)slab * SLAB + (prow * PD + pcol) * 8] = z;
    }
}

// ---- pack weights: w[co][ci][tap] f32 -> wp[coblk][chunk][tap][half][co128][8ci] bf16 ----
__global__ void pack_w(const float* __restrict__ w1, const float* __restrict__ w2,
                       __bf16* __restrict__ wp1, __bf16* __restrict__ wp2) {
    int id = blockIdx.x * 256 + threadIdx.x;     // < 589824
    const float* w = blockIdx.y ? w2 : w1;
    __bf16* wp = blockIdx.y ? wp2 : wp1;
    int j = id & 7; int t = id >> 3;
    int col = t & 127; t >>= 7;
    int half = t & 1; t >>= 1;
    int tap = t % 9; t /= 9;
    int chunk = t & 15; int coblk = t >> 4;
    int co = coblk * 128 + col;
    int ci = chunk * 16 + half * 8 + j;
    wp[id] = (__bf16)(w[((size_t)co * Cc + ci) * 9 + tap]);
}

// ---- fold BN params ----
__global__ void bn_prep(const float* g1, const float* b1, const float* m1, const float* v1,
                        const float* g2, const float* b2, const float* m2, const float* v2,
                        float* binv1, float* bbeta1, float* binv2, float* bbeta2) {
    int c = threadIdx.x;
    float i1 = g1[c] * rsqrtf(v1[c] + EPS);
    binv1[c] = i1; bbeta1[c] = b1[c] - m1[c] * i1;
    float i2 = g2[c] * rsqrtf(v2[c] + EPS);
    binv2[c] = i2; bbeta2[c] = b2[c] - m2[c] * i2;
}

__device__ __forceinline__ void gl_lds16(const __bf16* g, __bf16* l) {
    __builtin_amdgcn_global_load_lds(
        (const __attribute__((address_space(1))) void*)g,
        (__attribute__((address_space(3))) void*)l, 16, 0, 0);
}

template <bool C1>
__global__ __launch_bounds__(512, 4)
void conv_kern(const __bf16* __restrict__ src,   // xm (conv1) or u (conv2), chunk-major
               const __bf16* __restrict__ wp,    // packed weights
               const float* __restrict__ maskg,  // mask [B,HW]
               const float* __restrict__ vec,    // vector [B,C] (conv1 only)
               const float* __restrict__ binv, const float* __restrict__ bbeta,
               const float* __restrict__ xin,    // identity x NCHW f32 (conv2 only)
               void* __restrict__ dstv) {
    constexpr int SINB = 2 * 10 * 66 * 8;        // 10560 elems = 21120 B
    constexpr int SWB  = 9 * 2 * 128 * 8;        // 18432 elems = 36864 B
    __shared__ __align__(16) __bf16 s_in[SINB];  // single buffer
    __shared__ __align__(16) __bf16 s_w[SWB];    // single buffer   (total 58 KB)

    const int tid = threadIdx.x;
    const int lane = tid & 63, wave = tid >> 6;
    const int xlane = lane & 31, halfid = lane >> 5;
    const int pxw = wave >> 1, cow = wave & 1;   // 4 px groups x 2 co halves

    // XCD-bijective swizzle (448 = 8*56): each XCD gets 4 whole images
    const int bid = blockIdx.x;
    const int wg = (bid & 7) * 56 + (bid >> 3);
    const int img = wg / 14;
    const int t = wg - img * 14;
    const int y0 = (t >> 1) * 8;                 // band of 8 output rows
    const int coblk = t & 1;
    const int co0c = coblk * 128;

    f32x16 acc[4][2];
    #pragma unroll
    for (int a = 0; a < 4; ++a)
        #pragma unroll
        for (int b = 0; b < 2; ++b)
            #pragma unroll
            for (int r = 0; r < 16; ++r) acc[a][b][r] = 0.f;

    const __bf16* wblk = wp + (size_t)coblk * (16 * SWB);
    const float* maskp = maskg + (size_t)img * HW;
    const __bf16* srcimg = src + (size_t)img * IMG_ELEMS;

    // ---- staging (uniform per-wave issue counts; all loads coalesced) ----
    auto STAGE_IN = [&](int chunk) {             // 1320 units = 8 waves * 165
        const __bf16* slab = srcimg + (size_t)chunk * (2 * SLAB);
        const int base = wave * 165;
        #pragma unroll
        for (int k = 0; k < 3; ++k) {
            int u0 = base + k * 64;
            int u = u0 + lane;
            if (u < base + 165) {
                int half = u / 660, rem = u - half * 660;
                int row = rem / 66, xx = rem - row * 66;
                int pcol = xx < PD ? xx : PD - 1;   // clamp: feeds dead outputs only
                gl_lds16(slab + ((size_t)half * SLAB) +
                             ((y0 + row) * PD + pcol) * 8,
                         &s_in[u0 * 8]);
            }
        }
    };
    auto STAGE_W = [&](int chunk) {              // 2304 units = 8 waves * 288
        const __bf16* g = wblk + (size_t)chunk * SWB;
        const int base = wave * 288;
        #pragma unroll
        for (int k = 0; k < 5; ++k) {
            int u0 = base + k * 64;
            int u = u0 + lane;
            if (u < base + 288)
                gl_lds16(g + (size_t)u * 8, &s_w[u0 * 8]);
        }
    };

    for (int c = 0; c < 16; ++c) {
        // ---- stage chunk c (single buffer) ----
        STAGE_W(c);
        STAGE_IN(c);
        asm volatile("s_waitcnt vmcnt(0)" ::: "memory");
        __builtin_amdgcn_sched_barrier(0);
        __builtin_amdgcn_s_barrier();
        __builtin_amdgcn_sched_barrier(0);

        // ---- compute: 9 taps x 8 mfma ----
        __builtin_amdgcn_s_setprio(1);
        #pragma unroll
        for (int kh = 0; kh < 3; ++kh)
            #pragma unroll
            for (int kw = 0; kw < 3; ++kw) {
                const int tap = kh * 3 + kw;
                bf16x8 wf[2], inf[4];
                #pragma unroll
                for (int jt = 0; jt < 2; ++jt)
                    wf[jt] = *(const bf16x8*)&s_w[((tap * 2 + halfid) * 128 +
                                                   (cow * 2 + jt) * 32 + xlane) * 8];
                #pragma unroll
                for (int it = 0; it < 4; ++it) {
                    int tg = pxw * 4 + it;
                    int yy = (tg >> 1) + kh;
                    int xx = (tg & 1) * 32 + xlane + kw;
                    inf[it] = *(const bf16x8*)&s_in[((halfid * 10 + yy) * 66 + xx) * 8];
                }
                #pragma unroll
                for (int it = 0; it < 4; ++it)
                    #pragma unroll
                    for (int jt = 0; jt < 2; ++jt) {
                        if constexpr (C1)
                            acc[it][jt] = __builtin_amdgcn_mfma_f32_32x32x16_bf16(
                                inf[it], wf[jt], acc[it][jt], 0, 0, 0);
                        else
                            acc[it][jt] = __builtin_amdgcn_mfma_f32_32x32x16_bf16(
                                wf[jt], inf[it], acc[it][jt], 0, 0, 0);
                    }
            }
        __builtin_amdgcn_s_setprio(0);
        __builtin_amdgcn_sched_barrier(0);
        __builtin_amdgcn_s_barrier();            // all waves done reading buffers
        __builtin_amdgcn_sched_barrier(0);
    }

    // ---- epilogue ----
    if constexpr (C1) {
        // D: row = pixel, col(lane&31) = co. Store u chunk-major bf16.
        __bf16* u = (__bf16*)dstv;
        float iv[2], bt[2], vv[2]; int cog[2]; size_t slb[2];
        #pragma unroll
        for (int jt = 0; jt < 2; ++jt) {
            cog[jt] = co0c + (cow * 2 + jt) * 32 + xlane;
            iv[jt] = binv[cog[jt]];
            bt[jt] = bbeta[cog[jt]];
            vv[jt] = vec[img * Cc + cog[jt]];
            slb[jt] = (size_t)(img * 32 + (cog[jt] >> 3)) * SLAB + (cog[jt] & 7);
        }
        #pragma unroll
        for (int it = 0; it < 4; ++it) {
            int tg = pxw * 4 + it;
            int y = y0 + (tg >> 1), xb = (tg & 1) * 32;
            #pragma unroll
            for (int reg = 0; reg < 16; ++reg) {
                int x = xb + (reg & 3) + 8 * (reg >> 2) + 4 * halfid;
                if (x < 56) {
                    float mv = maskp[y * 56 + x];
                    int poff = ((y + 1) * PD + (x + 1)) * 8;
                    #pragma unroll
                    for (int jt = 0; jt < 2; ++jt) {
                        float o = fmaxf(fmaf(acc[it][jt][reg], iv[jt], bt[jt]), 0.f)
                                  * mv * vv[jt];
                        u[slb[jt] + poff] = (__bf16)o;
                    }
                }
            }
        }
    } else {
        // D: row = co, col(lane&31) = pixel. Store out NCHW f32 with identity+relu.
        float* outp = (float*)dstv;
        int ya[4], xa[4]; float mva[4]; bool ok[4];
        #pragma unroll
        for (int it = 0; it < 4; ++it) {
            int tg = pxw * 4 + it;
            ya[it] = y0 + (tg >> 1);
            xa[it] = (tg & 1) * 32 + xlane;
            ok[it] = xa[it] < 56;
            mva[it] = ok[it] ? maskp[ya[it] * 56 + xa[it]] : 0.f;
        }
        #pragma unroll
        for (int jt = 0; jt < 2; ++jt) {
            int cb = co0c + (cow * 2 + jt) * 32;
            #pragma unroll
            for (int rg = 0; rg < 4; ++rg) {
                int c4 = cb + 8 * rg + 4 * halfid;
                float4 iv4 = *(const float4*)&binv[c4];
                float4 bt4 = *(const float4*)&bbeta[c4];
                float ivv[4] = {iv4.x, iv4.y, iv4.z, iv4.w};
                float btv[4] = {bt4.x, bt4.y, bt4.z, bt4.w};
                #pragma unroll
                for (int j = 0; j < 4; ++j) {
                    int reg = rg * 4 + j;
                    int co = c4 + j;
                    size_t cbase = (size_t)(img * Cc + co) * HW;
                    #pragma unroll
                    for (int it = 0; it < 4; ++it) {
                        if (ok[it]) {
                            size_t oa = cbase + ya[it] * 56 + xa[it];
                            float o = fmaxf(
                                xin[oa] + mva[it] * fmaf(acc[it][jt][reg], ivv[j], btv[j]),
                                0.f);
                            outp[oa] = o;
                        }
                    }
                }
            }
        }
    }
}

extern "C" void kernel_launch(void* const* d_in, const int* in_sizes, int n_in,
                              void* d_out, int out_size, void* d_ws, size_t ws_size,
                              hipStream_t stream) {
    const float* x    = (const float*)d_in[0];
    const float* mask = (const float*)d_in[1];
    const float* md   = (const float*)d_in[2];
    const float* vec  = (const float*)d_in[3];
    const float* w1   = (const float*)d_in[4];
    const float* bn1g = (const float*)d_in[5];
    const float* bn1b = (const float*)d_in[6];
    const float* bn1m = (const float*)d_in[7];
    const float* bn1v = (const float*)d_in[8];
    const float* w2   = (const float*)d_in[9];
    const float* bn2g = (const float*)d_in[10];
    const float* bn2b = (const float*)d_in[11];
    const float* bn2m = (const float*)d_in[12];
    const float* bn2v = (const float*)d_in[13];
    float* out = (float*)d_out;

    const size_t npad = (size_t)Bn * IMG_ELEMS;  // 27,557,888 elems (55.1 MB bf16)
    __bf16* xm  = (__bf16*)d_ws;
    __bf16* u   = xm + npad;
    __bf16* wp1 = u + npad;
    __bf16* wp2 = wp1 + WP_ELEMS;
    float* binv1  = (float*)(wp2 + WP_ELEMS);
    float* bbeta1 = binv1 + 256;
    float* binv2  = bbeta1 + 256;
    float* bbeta2 = binv2 + 256;

    pack_xm<<<dim3(PD, Bn), dim3(256), 0, stream>>>(x, md, xm);
    zero_u_halo<<<dim3(Bn), dim3(256), 0, stream>>>(u);
    pack_w<<<dim3(WP_ELEMS / 256, 2), dim3(256), 0, stream>>>(w1, w2, wp1, wp2);
    bn_prep<<<dim3(1), dim3(256), 0, stream>>>(bn1g, bn1b, bn1m, bn1v,
                                               bn2g, bn2b, bn2m, bn2v,
                                               binv1, bbeta1, binv2, bbeta2);

    conv_kern<true><<<dim3(448), dim3(512), 0, stream>>>(
        xm, wp1, mask, vec, binv1, bbeta1, nullptr, u);
    conv_kern<false><<<dim3(448), dim3(512), 0, stream>>>(
        u, wp2, mask, nullptr, binv2, bbeta2, x, out);
}

// Round 5
// 524.831 us; speedup vs baseline: 8.0444x; 8.0444x over previous
//
#include <hip/hip_runtime.h>
#include <cstdint>

// Sparse BasicBlock via bf16 MFMA implicit GEMM (32x32x16).
// Round 5: REGISTER-LEAN tiles for real occupancy. acc[2][2] (64 acc regs vs 128)
// so total regs ~150 -> 3 waves/SIMD. 256-thr blocks (4 waves), 45.3 KB LDS ->
// 3 independent blocks/CU (12 waves/CU), anti-phased barriers hide stage drains.
// R4 lesson: launch_bounds reg cap below acc size => scratch spill (9 GB HBM!).
//   xm,u layout: [img][chunk16][half2][row58][col58][c8]  (halo zero) — staging
//   order == storage order, so every global_load_lds is fully coalesced.
//   u   = mask * vector * relu(bn1(conv1(x * mask_dilate)))
//   out = relu(x + mask * bn2(conv2(u)))                      [NCHW f32]

#define EPS 1e-5f

constexpr int Bn = 32, Cc = 256, Hh = 56, Ww = 56;
constexpr int HW = Hh * Ww;                 // 3136
constexpr int PD = 58;                      // padded H/W
constexpr int SLAB = PD * PD * 8;           // elems per [row][col][c8] slab = 26912
constexpr int IMG_ELEMS = 16 * 2 * SLAB;    // 861184 elems per image
constexpr int WP_ELEMS = 2 * 16 * 9 * 2 * 128 * 8;   // 589824 per conv

typedef __bf16 bf16x8 __attribute__((ext_vector_type(8)));
typedef float  f32x16 __attribute__((ext_vector_type(16)));

// ---- pack x*mask_dilate -> chunk-major staged bf16, halo zeros ----
__global__ void pack_xm(const float* __restrict__ x, const float* __restrict__ md,
                        __bf16* __restrict__ xm) {
    int prow = blockIdx.x, img = blockIdx.y;
    int gy = prow - 1;
    bool rv = (unsigned)gy < 56u;
    for (int u = threadIdx.x; u < 32 * 64; u += 256) {
        int cg = u >> 6, pcol = u & 63;          // cg = chunk*2+half (32 groups of 8ch)
        if (pcol >= PD) continue;
        int gx = pcol - 1;
        bf16x8 v = {};
        if (rv && (unsigned)gx < 56u) {
            float mdv = md[img * HW + gy * 56 + gx];
            const float* xp = x + ((size_t)img * Cc + cg * 8) * HW + gy * 56 + gx;
            #pragma unroll
            for (int j = 0; j < 8; ++j)
                v[j] = (__bf16)(xp[(size_t)j * HW] * mdv);
        }
        *(bf16x8*)&xm[(size_t)(img * 32 + cg) * SLAB + (prow * PD + pcol) * 8] = v;
    }
}

// ---- zero the halo of u (rows 0,57; cols 0,57 of every slab) ----
__global__ void zero_u_halo(__bf16* __restrict__ u) {
    int img = blockIdx.x;
    __bf16* base = u + (size_t)img * IMG_ELEMS;
    bf16x8 z = {};
    for (int t = threadIdx.x; t < 32 * 228; t += 256) {
        int slab = t / 228, site = t - slab * 228;
        int prow, pcol;
        if (site < 58)       { prow = 0;          pcol = site; }
        else if (site < 116) { prow = 57;         pcol = site - 58; }
        else if (site < 172) { prow = site - 115; pcol = 0; }
        else                 { prow = site - 171; pcol = 57; }
        *(bf16x8*)&base[(size_t)slab * SLAB + (prow * PD + pcol) * 8] = z;
    }
}

// ---- pack weights: w[co][ci][tap] f32 -> wp[coblk][chunk][tap][half][co128][8ci] bf16 ----
__global__ void pack_w(const float* __restrict__ w1, const float* __restrict__ w2,
                       __bf16* __restrict__ wp1, __bf16* __restrict__ wp2) {
    int id = blockIdx.x * 256 + threadIdx.x;     // < 589824
    const float* w = blockIdx.y ? w2 : w1;
    __bf16* wp = blockIdx.y ? wp2 : wp1;
    int j = id & 7; int t = id >> 3;
    int col = t & 127; t >>= 7;
    int half = t & 1; t >>= 1;
    int tap = t % 9; t /= 9;
    int chunk = t & 15; int coblk = t >> 4;
    int co = coblk * 128 + col;
    int ci = chunk * 16 + half * 8 + j;
    wp[id] = (__bf16)(w[((size_t)co * Cc + ci) * 9 + tap]);
}

// ---- fold BN params ----
__global__ void bn_prep(const float* g1, const float* b1, const float* m1, const float* v1,
                        const float* g2, const float* b2, const float* m2, const float* v2,
                        float* binv1, float* bbeta1, float* binv2, float* bbeta2) {
    int c = threadIdx.x;
    float i1 = g1[c] * rsqrtf(v1[c] + EPS);
    binv1[c] = i1; bbeta1[c] = b1[c] - m1[c] * i1;
    float i2 = g2[c] * rsqrtf(v2[c] + EPS);
    binv2[c] = i2; bbeta2[c] = b2[c] - m2[c] * i2;
}

__device__ __forceinline__ void gl_lds16(const __bf16* g, __bf16* l) {
    __builtin_amdgcn_global_load_lds(
        (const __attribute__((address_space(1))) void*)g,
        (__attribute__((address_space(3))) void*)l, 16, 0, 0);
}

template <bool C1>
__global__ __launch_bounds__(256, 3)
void conv_kern(const __bf16* __restrict__ src,   // xm (conv1) or u (conv2), chunk-major
               const __bf16* __restrict__ wp,    // packed weights
               const float* __restrict__ maskg,  // mask [B,HW]
               const float* __restrict__ vec,    // vector [B,C] (conv1 only)
               const float* __restrict__ binv, const float* __restrict__ bbeta,
               const float* __restrict__ xin,    // identity x NCHW f32 (conv2 only)
               void* __restrict__ dstv) {
    constexpr int SINB = 2 * 4 * 66 * 8;         // 4224 elems = 8448 B
    constexpr int SWB  = 9 * 2 * 128 * 8;        // 18432 elems = 36864 B
    __shared__ __align__(16) __bf16 s_in[SINB];
    __shared__ __align__(16) __bf16 s_w[SWB];    // total 45312 B -> 3 blocks/CU

    const int tid = threadIdx.x;
    const int lane = tid & 63, wave = tid >> 6;  // 4 waves
    const int xlane = lane & 31, halfid = lane >> 5;
    const int pxg = wave >> 1, cog = wave & 1;   // 2 px rows x 2 co halves

    // XCD-bijective swizzle (1792 = 8*224): each XCD gets 4 whole images
    const int bid = blockIdx.x;
    const int wg = (bid & 7) * 224 + (bid >> 3);
    const int img = wg / 56;
    const int t = wg - img * 56;
    const int y0 = (t >> 1) * 2;                 // band of 2 output rows
    const int coblk = t & 1;
    const int co0c = coblk * 128;

    f32x16 acc[2][2];
    #pragma unroll
    for (int a = 0; a < 2; ++a)
        #pragma unroll
        for (int b = 0; b < 2; ++b)
            #pragma unroll
            for (int r = 0; r < 16; ++r) acc[a][b][r] = 0.f;

    const __bf16* wblk = wp + (size_t)coblk * (16 * SWB);
    const float* maskp = maskg + (size_t)img * HW;
    const __bf16* srcimg = src + (size_t)img * IMG_ELEMS;

    // ---- staging: all loads coalesced (storage order == enumeration order) ----
    // input window: padded rows y0..y0+3, 66 cols, 16 ci -> 528 16B-units
    auto STAGE_IN = [&](int chunk) {
        const __bf16* slab = srcimg + (size_t)chunk * (2 * SLAB);
        #pragma unroll
        for (int k = 0; k < 3; ++k) {
            int u0 = wave * 64 + k * 256;        // wave-uniform base unit
            int u = u0 + lane;
            if (u < 528) {
                int half = u / 264, rem = u - half * 264;
                int row = rem / 66, xx = rem - row * 66;
                int pcol = xx < PD ? xx : PD - 1;   // clamp: feeds dead outputs only
                gl_lds16(slab + ((size_t)half * SLAB) + ((y0 + row) * PD + pcol) * 8,
                         &s_in[u0 * 8]);
            }
        }
    };
    auto STAGE_W = [&](int chunk) {              // 2304 units = 9 * 256
        const __bf16* g = wblk + (size_t)chunk * SWB;
        #pragma unroll
        for (int k = 0; k < 9; ++k) {
            int u0 = wave * 64 + k * 256;
            gl_lds16(g + (size_t)(u0 + lane) * 8, &s_w[u0 * 8]);
        }
    };

    for (int c = 0; c < 16; ++c) {
        STAGE_W(c);
        STAGE_IN(c);
        asm volatile("s_waitcnt vmcnt(0)" ::: "memory");
        __builtin_amdgcn_sched_barrier(0);
        __builtin_amdgcn_s_barrier();
        __builtin_amdgcn_sched_barrier(0);

        __builtin_amdgcn_s_setprio(1);
        #pragma unroll
        for (int kh = 0; kh < 3; ++kh)
            #pragma unroll
            for (int kw = 0; kw < 3; ++kw) {
                const int tap = kh * 3 + kw;
                bf16x8 wf[2], inf[2];
                #pragma unroll
                for (int jt = 0; jt < 2; ++jt)
                    wf[jt] = *(const bf16x8*)&s_w[((tap * 2 + halfid) * 128 +
                                                   (cog * 2 + jt) * 32 + xlane) * 8];
                #pragma unroll
                for (int it = 0; it < 2; ++it) {
                    int yy = pxg + kh;           // 0..3 within 4-row window
                    int xx = it * 32 + xlane + kw;
                    inf[it] = *(const bf16x8*)&s_in[((halfid * 4 + yy) * 66 + xx) * 8];
                }
                #pragma unroll
                for (int it = 0; it < 2; ++it)
                    #pragma unroll
                    for (int jt = 0; jt < 2; ++jt) {
                        if constexpr (C1)
                            acc[it][jt] = __builtin_amdgcn_mfma_f32_32x32x16_bf16(
                                inf[it], wf[jt], acc[it][jt], 0, 0, 0);
                        else
                            acc[it][jt] = __builtin_amdgcn_mfma_f32_32x32x16_bf16(
                                wf[jt], inf[it], acc[it][jt], 0, 0, 0);
                    }
            }
        __builtin_amdgcn_s_setprio(0);
        __builtin_amdgcn_sched_barrier(0);
        __builtin_amdgcn_s_barrier();            // all waves done reading buffers
        __builtin_amdgcn_sched_barrier(0);
    }

    // ---- epilogue ----
    const int y = y0 + pxg;                      // this wave's single output row
    if constexpr (C1) {
        // D: row = pixel-x (reg formula), col(lane&31) = co. Store u chunk-major bf16.
        __bf16* u = (__bf16*)dstv;
        float iv[2], bt[2], vv[2]; int cog2[2]; size_t slb[2];
        #pragma unroll
        for (int jt = 0; jt < 2; ++jt) {
            cog2[jt] = co0c + (cog * 2 + jt) * 32 + xlane;
            iv[jt] = binv[cog2[jt]];
            bt[jt] = bbeta[cog2[jt]];
            vv[jt] = vec[img * Cc + cog2[jt]];
            slb[jt] = (size_t)(img * 32 + (cog2[jt] >> 3)) * SLAB + (cog2[jt] & 7);
        }
        #pragma unroll
        for (int it = 0; it < 2; ++it) {
            int xb = it * 32;
            #pragma unroll
            for (int reg = 0; reg < 16; ++reg) {
                int x = xb + (reg & 3) + 8 * (reg >> 2) + 4 * halfid;
                if (x < 56) {
                    float mv = maskp[y * 56 + x];
                    int poff = ((y + 1) * PD + (x + 1)) * 8;
                    #pragma unroll
                    for (int jt = 0; jt < 2; ++jt) {
                        float o = fmaxf(fmaf(acc[it][jt][reg], iv[jt], bt[jt]), 0.f)
                                  * mv * vv[jt];
                        u[slb[jt] + poff] = (__bf16)o;
                    }
                }
            }
        }
    } else {
        // D: row = co (reg formula), col(lane&31) = pixel. Store NCHW f32 + identity+relu.
        float* outp = (float*)dstv;
        int xa[2]; float mva[2]; bool ok[2];
        #pragma unroll
        for (int it = 0; it < 2; ++it) {
            xa[it] = it * 32 + xlane;
            ok[it] = xa[it] < 56;
            mva[it] = ok[it] ? maskp[y * 56 + xa[it]] : 0.f;
        }
        #pragma unroll
        for (int jt = 0; jt < 2; ++jt) {
            int cb = co0c + (cog * 2 + jt) * 32;
            #pragma unroll
            for (int rg = 0; rg < 4; ++rg) {
                int c4 = cb + 8 * rg + 4 * halfid;
                float4 iv4 = *(const float4*)&binv[c4];
                float4 bt4 = *(const float4*)&bbeta[c4];
                float ivv[4] = {iv4.x, iv4.y, iv4.z, iv4.w};
                float btv[4] = {bt4.x, bt4.y, bt4.z, bt4.w};
                #pragma unroll
                for (int j = 0; j < 4; ++j) {
                    int reg = rg * 4 + j;
                    int co = c4 + j;
                    size_t cbase = (size_t)(img * Cc + co) * HW;
                    #pragma unroll
                    for (int it = 0; it < 2; ++it) {
                        if (ok[it]) {
                            size_t oa = cbase + y * 56 + xa[it];
                            float o = fmaxf(
                                xin[oa] + mva[it] * fmaf(acc[it][jt][reg], ivv[j], btv[j]),
                                0.f);
                            outp[oa] = o;
                        }
                    }
                }
            }
        }
    }
}

extern "C" void kernel_launch(void* const* d_in, const int* in_sizes, int n_in,
                              void* d_out, int out_size, void* d_ws, size_t ws_size,
                              hipStream_t stream) {
    const float* x    = (const float*)d_in[0];
    const float* mask = (const float*)d_in[1];
    const float* md   = (const float*)d_in[2];
    const float* vec  = (const float*)d_in[3];
    const float* w1   = (const float*)d_in[4];
    const float* bn1g = (const float*)d_in[5];
    const float* bn1b = (const float*)d_in[6];
    const float* bn1m = (const float*)d_in[7];
    const float* bn1v = (const float*)d_in[8];
    const float* w2   = (const float*)d_in[9];
    const float* bn2g = (const float*)d_in[10];
    const float* bn2b = (const float*)d_in[11];
    const float* bn2m = (const float*)d_in[12];
    const float* bn2v = (const float*)d_in[13];
    float* out = (float*)d_out;

    const size_t npad = (size_t)Bn * IMG_ELEMS;  // 27,557,888 elems (55.1 MB bf16)
    __bf16* xm  = (__bf16*)d_ws;
    __bf16* u   = xm + npad;
    __bf16* wp1 = u + npad;
    __bf16* wp2 = wp1 + WP_ELEMS;
    float* binv1  = (float*)(wp2 + WP_ELEMS);
    float* bbeta1 = binv1 + 256;
    float* binv2  = bbeta1 + 256;
    float* bbeta2 = binv2 + 256;

    pack_xm<<<dim3(PD, Bn), dim3(256), 0, stream>>>(x, md, xm);
    zero_u_halo<<<dim3(Bn), dim3(256), 0, stream>>>(u);
    pack_w<<<dim3(WP_ELEMS / 256, 2), dim3(256), 0, stream>>>(w1, w2, wp1, wp2);
    bn_prep<<<dim3(1), dim3(256), 0, stream>>>(bn1g, bn1b, bn1m, bn1v,
                                               bn2g, bn2b, bn2m, bn2v,
                                               binv1, bbeta1, binv2, bbeta2);

    // grid: 28 bands x 2 co-blocks x 32 images = 1792 = 7 per CU
    conv_kern<true><<<dim3(1792), dim3(256), 0, stream>>>(
        xm, wp1, mask, vec, binv1, bbeta1, nullptr, u);
    conv_kern<false><<<dim3(1792), dim3(256), 0, stream>>>(
        u, wp2, mask, nullptr, binv2, bbeta2, x, out);
}